// Round 21
// baseline (236.096 us; speedup 1.0000x reference)
//
#include <hip/hip_runtime.h>
#include <math.h>

#define NSPLIT 4
#define KB 64
#define SPLIT_KEYS 1024
#define NTILES (SPLIT_KEYS / KB)
#define NCOPYROWS 64   // rows per copy block; 512 copy blocks cover 8*4092

typedef float vfloat4 __attribute__((ext_vector_type(4)));

__device__ __forceinline__ float wsum(float v) {
#pragma unroll
  for (int off = 32; off >= 1; off >>= 1) v += __shfl_xor(v, off, 64);
  return v;
}
__device__ __forceinline__ float wmax(float v) {
#pragma unroll
  for (int off = 32; off >= 1; off >>= 1) v = fmaxf(v, __shfl_xor(v, off, 64));
  return v;
}
__device__ __forceinline__ float dot4(const float4 a, const float4 b) {
  return a.x * b.x + a.y * b.y + a.z * b.z + a.w * b.w;
}

// ---------------- proj1: c_q / c_kv_new / k_rope_new from hidden (K=2048) ----
__global__ __launch_bounds__(256) void proj1_kernel(
    const float* __restrict__ hidden, const float* __restrict__ W_dq,
    const float* __restrict__ W_dkv, const float* __restrict__ W_kr,
    float* __restrict__ ws_cq, float* __restrict__ out_ckv,
    float* __restrict__ out_kr) {
  const int wave = threadIdx.x >> 6;
  const int lane = threadIdx.x & 63;
  const int jbase = (blockIdx.x * 4 + wave) * 2;  // 2624 cols total
  const float* w0;
  if (jbase < 512)       w0 = W_dq  + (size_t)jbase * 2048;
  else if (jbase < 2560) w0 = W_dkv + (size_t)(jbase - 512) * 2048;
  else                   w0 = W_kr  + (size_t)(jbase - 2560) * 2048;
  const float* w1 = w0 + 2048;

  __shared__ float wlds[4][2][2048];  // 64 KB

#pragma unroll
  for (int m = 0; m < 8; ++m) {
    __builtin_amdgcn_global_load_lds(
        (const __attribute__((address_space(1))) void*)(w0 + (m << 8) + (lane << 2)),
        (__attribute__((address_space(3))) void*)&wlds[wave][0][m << 8], 16, 0, 0);
    __builtin_amdgcn_global_load_lds(
        (const __attribute__((address_space(1))) void*)(w1 + (m << 8) + (lane << 2)),
        (__attribute__((address_space(3))) void*)&wlds[wave][1][m << 8], 16, 0, 0);
  }
  __syncthreads();   // drains vmcnt; weights in LDS

  float acc0[32], acc1[32];
#pragma unroll
  for (int i = 0; i < 32; ++i) { acc0[i] = 0.f; acc1[i] = 0.f; }

#pragma unroll 1
  for (int m = 0; m < 8; ++m) {
    const int k = (lane << 2) + (m << 8);
    const float4 wa = *(const float4*)&wlds[wave][0][k];
    const float4 wb = *(const float4*)&wlds[wave][1][k];
#pragma unroll
    for (int i = 0; i < 32; ++i) {
      const float4 a = *(const float4*)(hidden + i * 2048 + k);
      acc0[i] += dot4(a, wa);
      acc1[i] += dot4(a, wb);
    }
  }
#pragma unroll
  for (int i = 0; i < 32; ++i) { acc0[i] = wsum(acc0[i]); acc1[i] = wsum(acc1[i]); }

  if (jbase >= 2560) {  // RoPE on k_rope_new, position = t
    const int r0 = jbase - 2560;  // even
    const float inv = powf(10000.f, -(float)r0 / 64.f);
    float cs[4], sn[4];
#pragma unroll
    for (int t = 0; t < 4; ++t) { cs[t] = cosf((float)t * inv); sn[t] = sinf((float)t * inv); }
#pragma unroll
    for (int i = 0; i < 32; ++i) {
      const int t = i & 3;
      const float x0 = acc0[i], x1 = acc1[i];
      acc0[i] = x0 * cs[t] - x1 * sn[t];
      acc1[i] = x0 * sn[t] + x1 * cs[t];
    }
  }

  float myval = 0.f;
#pragma unroll
  for (int i = 0; i < 32; ++i) {
    myval = (lane == i)      ? acc0[i] : myval;
    myval = (lane == i + 32) ? acc1[i] : myval;
  }
  const int mi = lane & 31;               // row (b*4+t)
  const int col = jbase + (lane >> 5);
  const int b = mi >> 2, t = mi & 3;
  if (col < 512)
    ws_cq[mi * 512 + col] = myval;
  else if (col < 2560)
    out_ckv[((size_t)(b * 4096 + 4092 + t)) * 2048 + (col - 512)] = myval;
  else
    out_kr[((size_t)(b * 4096 + 4092 + t)) * 64 + (col - 2560)] = myval;
}

// ---------------- proj2: q_c / q_r (+RoPE) from c_q (K=512) ------------------
__global__ __launch_bounds__(256) void proj2_kernel(
    const float* __restrict__ cq, const float* __restrict__ W_uq,
    const float* __restrict__ W_qr, float* __restrict__ ws_qc,
    float* __restrict__ ws_qr) {
  const int wave = threadIdx.x >> 6;
  const int lane = threadIdx.x & 63;
  const int jbase = (blockIdx.x * 4 + wave) * 2;  // 3072 cols total
  const float* w0 = (jbase < 2048) ? (W_uq + (size_t)jbase * 512)
                                   : (W_qr + (size_t)(jbase - 2048) * 512);
  const float* w1 = w0 + 512;

  __shared__ float wlds[4][2][512];  // 16 KB

#pragma unroll
  for (int m = 0; m < 2; ++m) {
    __builtin_amdgcn_global_load_lds(
        (const __attribute__((address_space(1))) void*)(w0 + (m << 8) + (lane << 2)),
        (__attribute__((address_space(3))) void*)&wlds[wave][0][m << 8], 16, 0, 0);
    __builtin_amdgcn_global_load_lds(
        (const __attribute__((address_space(1))) void*)(w1 + (m << 8) + (lane << 2)),
        (__attribute__((address_space(3))) void*)&wlds[wave][1][m << 8], 16, 0, 0);
  }
  __syncthreads();

  float acc0[32], acc1[32];
#pragma unroll
  for (int i = 0; i < 32; ++i) { acc0[i] = 0.f; acc1[i] = 0.f; }

#pragma unroll 1
  for (int m = 0; m < 2; ++m) {
    const int k = (lane << 2) + (m << 8);
    const float4 wa = *(const float4*)&wlds[wave][0][k];
    const float4 wb = *(const float4*)&wlds[wave][1][k];
#pragma unroll
    for (int i = 0; i < 32; ++i) {
      const float4 a = *(const float4*)(cq + i * 512 + k);
      acc0[i] += dot4(a, wa);
      acc1[i] += dot4(a, wb);
    }
  }
#pragma unroll
  for (int i = 0; i < 32; ++i) { acc0[i] = wsum(acc0[i]); acc1[i] = wsum(acc1[i]); }

  if (jbase >= 2048) {  // RoPE on q_r, position = t
    const int r0 = (jbase - 2048) & 63;  // even
    const float inv = powf(10000.f, -(float)r0 / 64.f);
    float cs[4], sn[4];
#pragma unroll
    for (int t = 0; t < 4; ++t) { cs[t] = cosf((float)t * inv); sn[t] = sinf((float)t * inv); }
#pragma unroll
    for (int i = 0; i < 32; ++i) {
      const int t = i & 3;
      const float x0 = acc0[i], x1 = acc1[i];
      acc0[i] = x0 * cs[t] - x1 * sn[t];
      acc1[i] = x0 * sn[t] + x1 * cs[t];
    }
  }

  float myval = 0.f;
#pragma unroll
  for (int i = 0; i < 32; ++i) {
    myval = (lane == i)      ? acc0[i] : myval;
    myval = (lane == i + 32) ? acc1[i] : myval;
  }
  const int mi = lane & 31;
  const int col = jbase + (lane >> 5);
  if (col < 2048) ws_qc[mi * 2048 + col] = myval;
  else            ws_qr[mi * 1024 + (col - 2048)] = myval;
}

// ---------------- rope scores: rope[b][h*4+t][s] = q_r . k_rope  -------------
__global__ __launch_bounds__(256) void rope_kernel(
    const float* __restrict__ kr_past, float* __restrict__ out_kr,
    const float* __restrict__ qr_g, float* __restrict__ rope) {
  const int chunk = blockIdx.x;  // 64 keys per chunk
  const int b = blockIdx.y;
  const int tid = threadIdx.x;
  const int wave = tid >> 6;
  const int lane = tid & 63;
  const int s0 = chunk * 64;

  __shared__ float krt[64][68];
  __shared__ float sc[64][65];

#pragma unroll
  for (int u = 0; u < 4; ++u) {
    const int fi = tid + u * 256;
    const int row = fi >> 4;
    const int c4  = (fi & 15) << 2;
    const int s = s0 + row;
    float4 v;
    if (s < 4092) {
      v = *(const float4*)(kr_past + ((size_t)b * 4092 + s) * 64 + c4);
      __builtin_nontemporal_store(
          *(const vfloat4*)&v,
          (vfloat4*)(out_kr + ((size_t)(b * 4096 + s)) * 64 + c4));
    } else {
      v = *(const float4*)(out_kr + ((size_t)(b * 4096 + s)) * 64 + c4);
    }
    *(float4*)&krt[row][c4] = v;
  }

  float4 q[16];
  {
    const float* qrp = qr_g + ((size_t)(b * 4 + (lane & 3))) * 1024 + (lane >> 2) * 64;
#pragma unroll
    for (int m = 0; m < 16; ++m) q[m] = *(const float4*)(qrp + (m << 2));
  }
  __syncthreads();

#pragma unroll 1
  for (int j = 0; j < 16; ++j) {
    const int sl = wave * 16 + j;
    float sum = 0.f;
#pragma unroll
    for (int r = 0; r < 16; ++r) {
      const float4 kv4 = *(const float4*)&krt[sl][r << 2];
      sum += dot4(q[r], kv4);
    }
    sc[lane][sl] = sum;
  }
  __syncthreads();

#pragma unroll
  for (int u = 0; u < 16; ++u) {
    const int e = tid + u * 256;
    const int ht = e >> 6, sl = e & 63;
    rope[((size_t)b * 64 + ht) * 4096 + s0 + sl] = sc[ht][sl];
  }
}

// ---------------- fused attn + copy dispatch ---------------------------------
// Even blocks: pure streaming copy ckv_past -> out_ckv (fill-style contiguous
// 8KB rows, NT stores). Odd blocks: flash attention reading ckv_past ONLY
// (no copy-out, no store stream -> simple vmcnt(8)). Both roles read the same
// 268MB ckv_past in one dispatch: second consumer hits L3 (256MB); proj-chain
// serialization cost of a standalone copy kernel is avoided.
__global__ __launch_bounds__(256) void attn_copy_kernel(
    const float* __restrict__ ckv_past, float* __restrict__ out_ckv,
    const float* __restrict__ qc_g, const float* __restrict__ rope,
    float* __restrict__ part_acc, float* __restrict__ part_ml) {
  const int tid  = threadIdx.x;

  if ((blockIdx.x & 1) == 0) {
    // ---------------- copy role: 64 contiguous rows ----------------
    const int j = blockIdx.x >> 1;          // 0..511
    long r = (long)j * NCOPYROWS;
    int b = (int)(r / 4092);
    int s = (int)(r % 4092);
    const int o0 = tid << 2;                // 0..1023
#pragma unroll 4
    for (int rr = 0; rr < NCOPYROWS; ++rr) {
      if (b >= 8) break;
      const float* src = ckv_past + ((size_t)b * 4092 + s) * 2048;
      float* dst = out_ckv + ((size_t)(b * 4096 + s)) * 2048;
      const vfloat4 v0 = *(const vfloat4*)(src + o0);
      const vfloat4 v1 = *(const vfloat4*)(src + o0 + 1024);
      __builtin_nontemporal_store(v0, (vfloat4*)(dst + o0));
      __builtin_nontemporal_store(v1, (vfloat4*)(dst + o0 + 1024));
      if (++s == 4092) { s = 0; ++b; }
    }
    return;
  }

  // ---------------- attention role ----------------
  const int idx = blockIdx.x >> 1;        // 0..511
  const int sp = idx & 3;
  const int h  = (idx >> 2) & 15;
  const int b  = idx >> 6;
  const int wv   = tid >> 6;
  const int lane = tid & 63;
  const int t = wv;  // wave owns query position t

  __shared__ float kv[2][64][128];  // 64 KB (2 buffers)
  __shared__ float qc[4][128];

  // stage q for this (b,h)
#pragma unroll
  for (int rep = 0; rep < 2; ++rep) {
    const int idx2 = tid + rep * 256;
    const int tt = idx2 >> 7, d = idx2 & 127;
    qc[tt][d] = qc_g[((size_t)(b * 4 + tt)) * 2048 + h * 128 + d];
  }

  const float* rope_pt = rope + ((size_t)b * 64 + h * 4 + t) * 4096;
  const int lim = 4092 + t;       // inclusive causal limit
  const int s_begin = sp * SPLIT_KEYS;

  const int lrow = lane >> 5;     // 0..1
  const int pos  = lane & 31;     // 16B slot within row

  auto issue_tile = [&](int buf, int sbase) {
#pragma unroll
    for (int u = 0; u < 8; ++u) {
      const int row = 8 * u + 2 * wv + lrow;
      const int c = pos ^ (row & 7);           // source chunk for this LDS slot
      const int s = sbase + row;
      const float* src = (s < 4092)
          ? (ckv_past + ((size_t)b * 4092 + s) * 2048 + h * 128 + (c << 2))
          : (out_ckv + ((size_t)(b * 4096 + s)) * 2048 + h * 128 + (c << 2));
      __builtin_amdgcn_global_load_lds(
          (const __attribute__((address_space(1))) void*)src,
          (__attribute__((address_space(3))) void*)&kv[buf][8 * u + 2 * wv][0],
          16, 0, 0);
    }
  };

  issue_tile(0, s_begin);                         // prefetch tile 0
  asm volatile("s_waitcnt lgkmcnt(0)" ::: "memory");

  float m_run = -INFINITY, l_run = 0.f;
  float accX0 = 0.f, accX1 = 0.f;   // even kk partial
  float accY0 = 0.f, accY1 = 0.f;   // odd kk partial
  float rope_cur = rope_pt[s_begin + lane];
  int cur = 0;

#pragma unroll 1
  for (int tile = 0; tile < NTILES; ++tile) {
    const int s0 = s_begin + tile * KB;
    if (tile + 1 < NTILES) {
      issue_tile(cur ^ 1, s0 + KB);
      asm volatile("s_waitcnt vmcnt(8)" ::: "memory");   // current tile landed
    } else {
      asm volatile("s_waitcnt vmcnt(0)" ::: "memory");
    }
    __builtin_amdgcn_s_barrier();                 // all waves' rows in LDS

    __builtin_amdgcn_s_setprio(1);
    // prefetch next tile's rope value
    float rope_next = 0.f;
    if (tile + 1 < NTILES) rope_next = rope_pt[s0 + KB + lane];

    // scores: lane = key within tile, wave = query t; 2 partial sums (ILP)
    const int s = s0 + lane;
    float sc = -INFINITY;
    if (s <= lim) {
      float sumA = rope_cur, sumB = 0.f;
#pragma unroll
      for (int cc = 0; cc < 32; cc += 2) {
        const float4 kv0 = *(const float4*)&kv[cur][lane][(cc ^ (lane & 7)) << 2];
        const float4 kv1 = *(const float4*)&kv[cur][lane][((cc + 1) ^ (lane & 7)) << 2];
        sumA += dot4(kv0, *(const float4*)&qc[t][cc << 2]);
        sumB += dot4(kv1, *(const float4*)&qc[t][(cc + 1) << 2]);
      }
      sc = (sumA + sumB) * 0.07216878364870323f;  // 1/sqrt(192)
    }
    const float mt = wmax(sc);
    const float m_new = fmaxf(m_run, mt);
    const float p = expf(sc - m_new);   // masked: expf(-inf)=0
    const float lt = wsum(p);
    const float f = expf(m_run - m_new);
    l_run = l_run * f + lt;
    accX0 *= f; accX1 *= f; accY0 *= f; accY1 *= f;
    m_run = m_new;

    // PV: lane owns dims (2*lane, 2*lane+1); kk in pairs, 2 indep acc chains
    const int c0 = lane >> 1;
    const int off = (lane & 1) << 1;
    const int pu = __float_as_int(p);
#pragma unroll
    for (int kk = 0; kk < KB; kk += 2) {
      const float pv0 = __int_as_float(__builtin_amdgcn_readlane(pu, kk));
      const float pv1 = __int_as_float(__builtin_amdgcn_readlane(pu, kk + 1));
      const float2 vv0 = *(const float2*)&kv[cur][kk][((c0 ^ (kk & 7)) << 2) + off];
      const float2 vv1 = *(const float2*)&kv[cur][kk + 1][((c0 ^ ((kk + 1) & 7)) << 2) + off];
      accX0 += pv0 * vv0.x;
      accX1 += pv0 * vv0.y;
      accY0 += pv1 * vv1.x;
      accY1 += pv1 * vv1.y;
    }
    __builtin_amdgcn_s_setprio(0);

    __builtin_amdgcn_s_barrier();   // all waves done reading kv[cur]
    cur ^= 1;
    rope_cur = rope_next;
  }

  const size_t base = ((size_t)((b * 16 + h) * 4 + t)) * NSPLIT + sp;
  part_acc[base * 128 + (lane << 1)]     = accX0 + accY0;
  part_acc[base * 128 + (lane << 1) + 1] = accX1 + accY1;
  if (lane == 0) {
    part_ml[base * 2]     = m_run;
    part_ml[base * 2 + 1] = l_run;
  }
}

// ---------------- combine split partials -------------------------------------
__global__ __launch_bounds__(128) void combine_kernel(
    const float* __restrict__ part_acc, const float* __restrict__ part_ml,
    float* __restrict__ merged) {
  const int h = blockIdx.x & 15;
  const int b = blockIdx.x >> 4;
  const int d = threadIdx.x;  // 0..127
#pragma unroll
  for (int t = 0; t < 4; ++t) {
    const size_t base = ((size_t)((b * 16 + h) * 4 + t)) * NSPLIT;
    float mm[NSPLIT], ll[NSPLIT];
    float m = -INFINITY;
#pragma unroll
    for (int sp = 0; sp < NSPLIT; ++sp) {
      mm[sp] = part_ml[(base + sp) * 2];
      ll[sp] = part_ml[(base + sp) * 2 + 1];
      m = fmaxf(m, mm[sp]);
    }
    float den = 0.f, num = 0.f;
#pragma unroll
    for (int sp = 0; sp < NSPLIT; ++sp) {
      const float w = expf(mm[sp] - m);
      den += w * ll[sp];
      num += w * part_acc[(base + sp) * 128 + d];
    }
    merged[((size_t)(b * 4 + t)) * 2048 + h * 128 + d] = num / den;
  }
}

// ---------------- output projection (K=2048) ---------------------------------
__global__ __launch_bounds__(256) void outproj_kernel(
    const float* __restrict__ A, const float* __restrict__ W_o,
    float* __restrict__ out0) {
  const int wave = threadIdx.x >> 6;
  const int lane = threadIdx.x & 63;
  const int jbase = (blockIdx.x * 4 + wave) * 2;  // 2048 cols
  const float* w0 = W_o + (size_t)jbase * 2048;
  const float* w1 = w0 + 2048;

  __shared__ float wlds[4][2][2048];  // 64 KB

#pragma unroll
  for (int m = 0; m < 8; ++m) {
    __builtin_amdgcn_global_load_lds(
        (const __attribute__((address_space(1))) void*)(w0 + (m << 8) + (lane << 2)),
        (__attribute__((address_space(3))) void*)&wlds[wave][0][m << 8], 16, 0, 0);
    __builtin_amdgcn_global_load_lds(
        (const __attribute__((address_space(1))) void*)(w1 + (m << 8) + (lane << 2)),
        (__attribute__((address_space(3))) void*)&wlds[wave][1][m << 8], 16, 0, 0);
  }
  __syncthreads();

  float acc0[32], acc1[32];
#pragma unroll
  for (int i = 0; i < 32; ++i) { acc0[i] = 0.f; acc1[i] = 0.f; }

#pragma unroll 1
  for (int m = 0; m < 8; ++m) {
    const int k = (lane << 2) + (m << 8);
    const float4 wa = *(const float4*)&wlds[wave][0][k];
    const float4 wb = *(const float4*)&wlds[wave][1][k];
#pragma unroll
    for (int i = 0; i < 32; ++i) {
      const float4 a = *(const float4*)(A + i * 2048 + k);
      acc0[i] += dot4(a, wa);
      acc1[i] += dot4(a, wb);
    }
  }
#pragma unroll
  for (int i = 0; i < 32; ++i) { acc0[i] = wsum(acc0[i]); acc1[i] = wsum(acc1[i]); }
  float myval = 0.f;
#pragma unroll
  for (int i = 0; i < 32; ++i) {
    myval = (lane == i)      ? acc0[i] : myval;
    myval = (lane == i + 32) ? acc1[i] : myval;
  }
  const int mi = lane & 31;
  const int col = jbase + (lane >> 5);
  out0[(size_t)mi * 2048 + col] = myval;
}

extern "C" void kernel_launch(void* const* d_in, const int* in_sizes, int n_in,
                              void* d_out, int out_size, void* d_ws, size_t ws_size,
                              hipStream_t stream) {
  const float* hidden   = (const float*)d_in[0];
  const float* ckv_past = (const float*)d_in[1];
  const float* kr_past  = (const float*)d_in[2];
  // d_in[3] attention_mask: replicated analytically (causal, offset PAST)
  const float* W_dq  = (const float*)d_in[4];
  const float* W_uq  = (const float*)d_in[5];
  const float* W_qr  = (const float*)d_in[6];
  const float* W_dkv = (const float*)d_in[7];
  const float* W_kr  = (const float*)d_in[8];
  const float* W_o   = (const float*)d_in[9];

  float* out0    = (float*)d_out;                       // (8,4,2048)
  float* out_ckv = out0 + (size_t)32 * 2048;            // (8,4096,2048)
  float* out_kr  = out_ckv + (size_t)8 * 4096 * 2048;   // (8,4096,64)

  float* ws       = (float*)d_ws;
  float* ws_cq    = ws;                                  // 32*512
  float* ws_qc    = ws_cq + 32 * 512;                    // 32*2048
  float* ws_qr    = ws_qc + 32 * 2048;                   // 32*1024
  float* part_acc = ws_qr + 32 * 1024;                   // 8*16*4*NSPLIT*128
  float* part_ml  = part_acc + (size_t)8 * 16 * 4 * NSPLIT * 128;
  float* merged   = part_ml + (size_t)8 * 16 * 4 * NSPLIT * 2;   // 32*2048
  float* rope     = merged + 32 * 2048;                  // 8*64*4096 floats

  hipLaunchKernelGGL(proj1_kernel, dim3(328), dim3(256), 0, stream,
                     hidden, W_dq, W_dkv, W_kr, ws_cq, out_ckv, out_kr);
  hipLaunchKernelGGL(proj2_kernel, dim3(384), dim3(256), 0, stream,
                     ws_cq, W_uq, W_qr, ws_qc, ws_qr);
  hipLaunchKernelGGL(rope_kernel, dim3(64, 8), dim3(256), 0, stream,
                     kr_past, out_kr, ws_qr, rope);
  hipLaunchKernelGGL(attn_copy_kernel, dim3(1024), dim3(256), 0, stream,
                     ckv_past, out_ckv, ws_qc, rope, part_acc, part_ml);
  hipLaunchKernelGGL(combine_kernel, dim3(128), dim3(128), 0, stream,
                     part_acc, part_ml, merged);
  hipLaunchKernelGGL(outproj_kernel, dim3(256), dim3(256), 0, stream,
                     merged, W_o, out0);
}

// Round 22
// 188.528 us; speedup vs baseline: 1.2523x; 1.2523x over previous
//
#include <hip/hip_runtime.h>
#include <math.h>

#define NSPLIT 4
#define KB 64
#define SPLIT_KEYS 1024
#define NTILES (SPLIT_KEYS / KB)
#define AUX_NT 2   // gfx94x/gfx950 CPol: bit1 = NT (streaming, no L2 allocate)

typedef float vfloat4 __attribute__((ext_vector_type(4)));

__device__ __forceinline__ float wsum(float v) {
#pragma unroll
  for (int off = 32; off >= 1; off >>= 1) v += __shfl_xor(v, off, 64);
  return v;
}
__device__ __forceinline__ float wmax(float v) {
#pragma unroll
  for (int off = 32; off >= 1; off >>= 1) v = fmaxf(v, __shfl_xor(v, off, 64));
  return v;
}
__device__ __forceinline__ float dot4(const float4 a, const float4 b) {
  return a.x * b.x + a.y * b.y + a.z * b.z + a.w * b.w;
}

// ---------------- proj1: c_q / c_kv_new / k_rope_new from hidden (K=2048) ----
__global__ __launch_bounds__(256) void proj1_kernel(
    const float* __restrict__ hidden, const float* __restrict__ W_dq,
    const float* __restrict__ W_dkv, const float* __restrict__ W_kr,
    float* __restrict__ ws_cq, float* __restrict__ out_ckv,
    float* __restrict__ out_kr) {
  const int wave = threadIdx.x >> 6;
  const int lane = threadIdx.x & 63;
  const int jbase = (blockIdx.x * 4 + wave) * 2;  // 2624 cols total
  const float* w0;
  if (jbase < 512)       w0 = W_dq  + (size_t)jbase * 2048;
  else if (jbase < 2560) w0 = W_dkv + (size_t)(jbase - 512) * 2048;
  else                   w0 = W_kr  + (size_t)(jbase - 2560) * 2048;
  const float* w1 = w0 + 2048;

  __shared__ float wlds[4][2][2048];  // 64 KB

#pragma unroll
  for (int m = 0; m < 8; ++m) {
    __builtin_amdgcn_global_load_lds(
        (const __attribute__((address_space(1))) void*)(w0 + (m << 8) + (lane << 2)),
        (__attribute__((address_space(3))) void*)&wlds[wave][0][m << 8], 16, 0, AUX_NT);
    __builtin_amdgcn_global_load_lds(
        (const __attribute__((address_space(1))) void*)(w1 + (m << 8) + (lane << 2)),
        (__attribute__((address_space(3))) void*)&wlds[wave][1][m << 8], 16, 0, AUX_NT);
  }
  __syncthreads();   // drains vmcnt; weights in LDS

  float acc0[32], acc1[32];
#pragma unroll
  for (int i = 0; i < 32; ++i) { acc0[i] = 0.f; acc1[i] = 0.f; }

#pragma unroll 1
  for (int m = 0; m < 8; ++m) {
    const int k = (lane << 2) + (m << 8);
    const float4 wa = *(const float4*)&wlds[wave][0][k];
    const float4 wb = *(const float4*)&wlds[wave][1][k];
#pragma unroll
    for (int i = 0; i < 32; ++i) {
      const float4 a = *(const float4*)(hidden + i * 2048 + k);
      acc0[i] += dot4(a, wa);
      acc1[i] += dot4(a, wb);
    }
  }
#pragma unroll
  for (int i = 0; i < 32; ++i) { acc0[i] = wsum(acc0[i]); acc1[i] = wsum(acc1[i]); }

  if (jbase >= 2560) {  // RoPE on k_rope_new, position = t
    const int r0 = jbase - 2560;  // even
    const float inv = powf(10000.f, -(float)r0 / 64.f);
    float cs[4], sn[4];
#pragma unroll
    for (int t = 0; t < 4; ++t) { cs[t] = cosf((float)t * inv); sn[t] = sinf((float)t * inv); }
#pragma unroll
    for (int i = 0; i < 32; ++i) {
      const int t = i & 3;
      const float x0 = acc0[i], x1 = acc1[i];
      acc0[i] = x0 * cs[t] - x1 * sn[t];
      acc1[i] = x0 * sn[t] + x1 * cs[t];
    }
  }

  float myval = 0.f;
#pragma unroll
  for (int i = 0; i < 32; ++i) {
    myval = (lane == i)      ? acc0[i] : myval;
    myval = (lane == i + 32) ? acc1[i] : myval;
  }
  const int mi = lane & 31;               // row (b*4+t)
  const int col = jbase + (lane >> 5);
  const int b = mi >> 2, t = mi & 3;
  if (col < 512)
    ws_cq[mi * 512 + col] = myval;
  else if (col < 2560)
    out_ckv[((size_t)(b * 4096 + 4092 + t)) * 2048 + (col - 512)] = myval;
  else
    out_kr[((size_t)(b * 4096 + 4092 + t)) * 64 + (col - 2560)] = myval;
}

// ---------------- proj2: q_c / q_r (+RoPE) from c_q (K=512) ------------------
__global__ __launch_bounds__(256) void proj2_kernel(
    const float* __restrict__ cq, const float* __restrict__ W_uq,
    const float* __restrict__ W_qr, float* __restrict__ ws_qc,
    float* __restrict__ ws_qr) {
  const int wave = threadIdx.x >> 6;
  const int lane = threadIdx.x & 63;
  const int jbase = (blockIdx.x * 4 + wave) * 2;  // 3072 cols total
  const float* w0 = (jbase < 2048) ? (W_uq + (size_t)jbase * 512)
                                   : (W_qr + (size_t)(jbase - 2048) * 512);
  const float* w1 = w0 + 512;

  __shared__ float wlds[4][2][512];  // 16 KB

#pragma unroll
  for (int m = 0; m < 2; ++m) {
    __builtin_amdgcn_global_load_lds(
        (const __attribute__((address_space(1))) void*)(w0 + (m << 8) + (lane << 2)),
        (__attribute__((address_space(3))) void*)&wlds[wave][0][m << 8], 16, 0, AUX_NT);
    __builtin_amdgcn_global_load_lds(
        (const __attribute__((address_space(1))) void*)(w1 + (m << 8) + (lane << 2)),
        (__attribute__((address_space(3))) void*)&wlds[wave][1][m << 8], 16, 0, AUX_NT);
  }
  __syncthreads();

  float acc0[32], acc1[32];
#pragma unroll
  for (int i = 0; i < 32; ++i) { acc0[i] = 0.f; acc1[i] = 0.f; }

#pragma unroll 1
  for (int m = 0; m < 2; ++m) {
    const int k = (lane << 2) + (m << 8);
    const float4 wa = *(const float4*)&wlds[wave][0][k];
    const float4 wb = *(const float4*)&wlds[wave][1][k];
#pragma unroll
    for (int i = 0; i < 32; ++i) {
      const float4 a = *(const float4*)(cq + i * 512 + k);
      acc0[i] += dot4(a, wa);
      acc1[i] += dot4(a, wb);
    }
  }
#pragma unroll
  for (int i = 0; i < 32; ++i) { acc0[i] = wsum(acc0[i]); acc1[i] = wsum(acc1[i]); }

  if (jbase >= 2048) {  // RoPE on q_r, position = t
    const int r0 = (jbase - 2048) & 63;  // even
    const float inv = powf(10000.f, -(float)r0 / 64.f);
    float cs[4], sn[4];
#pragma unroll
    for (int t = 0; t < 4; ++t) { cs[t] = cosf((float)t * inv); sn[t] = sinf((float)t * inv); }
#pragma unroll
    for (int i = 0; i < 32; ++i) {
      const int t = i & 3;
      const float x0 = acc0[i], x1 = acc1[i];
      acc0[i] = x0 * cs[t] - x1 * sn[t];
      acc1[i] = x0 * sn[t] + x1 * cs[t];
    }
  }

  float myval = 0.f;
#pragma unroll
  for (int i = 0; i < 32; ++i) {
    myval = (lane == i)      ? acc0[i] : myval;
    myval = (lane == i + 32) ? acc1[i] : myval;
  }
  const int mi = lane & 31;
  const int col = jbase + (lane >> 5);
  if (col < 2048) ws_qc[mi * 2048 + col] = myval;
  else            ws_qr[mi * 1024 + (col - 2048)] = myval;
}

// ---------------- rope scores: rope[b][h*4+t][s] = q_r . k_rope  -------------
__global__ __launch_bounds__(256) void rope_kernel(
    const float* __restrict__ kr_past, float* __restrict__ out_kr,
    const float* __restrict__ qr_g, float* __restrict__ rope) {
  const int chunk = blockIdx.x;  // 64 keys per chunk
  const int b = blockIdx.y;
  const int tid = threadIdx.x;
  const int wave = tid >> 6;
  const int lane = tid & 63;
  const int s0 = chunk * 64;

  __shared__ float krt[64][68];
  __shared__ float sc[64][65];

#pragma unroll
  for (int u = 0; u < 4; ++u) {
    const int fi = tid + u * 256;
    const int row = fi >> 4;
    const int c4  = (fi & 15) << 2;
    const int s = s0 + row;
    float4 v;
    if (s < 4092) {
      v = *(const float4*)(kr_past + ((size_t)b * 4092 + s) * 64 + c4);
      __builtin_nontemporal_store(
          *(const vfloat4*)&v,
          (vfloat4*)(out_kr + ((size_t)(b * 4096 + s)) * 64 + c4));
    } else {
      v = *(const float4*)(out_kr + ((size_t)(b * 4096 + s)) * 64 + c4);
    }
    *(float4*)&krt[row][c4] = v;
  }

  float4 q[16];
  {
    const float* qrp = qr_g + ((size_t)(b * 4 + (lane & 3))) * 1024 + (lane >> 2) * 64;
#pragma unroll
    for (int m = 0; m < 16; ++m) q[m] = *(const float4*)(qrp + (m << 2));
  }
  __syncthreads();

#pragma unroll 1
  for (int j = 0; j < 16; ++j) {
    const int sl = wave * 16 + j;
    float sum = 0.f;
#pragma unroll
    for (int r = 0; r < 16; ++r) {
      const float4 kv4 = *(const float4*)&krt[sl][r << 2];
      sum += dot4(q[r], kv4);
    }
    sc[lane][sl] = sum;
  }
  __syncthreads();

#pragma unroll
  for (int u = 0; u < 16; ++u) {
    const int e = tid + u * 256;
    const int ht = e >> 6, sl = e & 63;
    rope[((size_t)b * 64 + ht) * 4096 + s0 + sl] = sc[ht][sl];
  }
}

// ---------------- flash attention + fused c_kv copy --------------------------
// r20 structure (best 189.2) + swizzle swap: XOR (c^(row&7)) had a 4-way PV
// bank conflict (4.2M measured, r13/r21); the additive rotation (c+2*row)&31
// measured 0 conflicts (r5). gload_lds writes linearly, so the SOURCE chunk
// for slot pos is the inverse permutation c = (pos - 2*row) & 31.
__global__ __launch_bounds__(256) void attn_kernel(
    const float* __restrict__ ckv_past, float* __restrict__ out_ckv,
    const float* __restrict__ qc_g, const float* __restrict__ rope,
    float* __restrict__ part_acc, float* __restrict__ part_ml) {
  const int sp = blockIdx.x;
  const int h  = blockIdx.y;
  const int b  = blockIdx.z;
  const int tid  = threadIdx.x;
  const int wv   = tid >> 6;
  const int lane = tid & 63;
  const int t = wv;  // wave owns query position t

  __shared__ float kv[2][64][128];  // 64 KB (2 buffers)
  __shared__ float qc[4][128];      //  2 KB -> 2 blocks/CU

  // stage q for this (b,h)
#pragma unroll
  for (int rep = 0; rep < 2; ++rep) {
    const int idx = tid + rep * 256;
    const int tt = idx >> 7, d = idx & 127;
    qc[tt][d] = qc_g[((size_t)(b * 4 + tt)) * 2048 + h * 128 + d];
  }

  const float* rope_pt = rope + ((size_t)b * 64 + h * 4 + t) * 4096;
  const int lim = 4092 + t;       // inclusive causal limit
  const int s_begin = sp * SPLIT_KEYS;

  const int lrow = lane >> 5;     // 0..1
  const int pos  = lane & 31;     // 16B slot within row

  auto issue_tile = [&](int buf, int sbase) {
#pragma unroll
    for (int u = 0; u < 8; ++u) {
      const int row = 8 * u + 2 * wv + lrow;
      const int c = (pos - 2 * row) & 31;      // inverse of slot=(c+2r)&31
      const int s = sbase + row;
      const float* src = (s < 4092)
          ? (ckv_past + ((size_t)b * 4092 + s) * 2048 + h * 128 + (c << 2))
          : (out_ckv + ((size_t)(b * 4096 + s)) * 2048 + h * 128 + (c << 2));
      __builtin_amdgcn_global_load_lds(
          (const __attribute__((address_space(1))) void*)src,
          (__attribute__((address_space(3))) void*)&kv[buf][8 * u + 2 * wv][0],
          16, 0, AUX_NT);
    }
  };

  issue_tile(0, s_begin);                         // prefetch tile 0
  asm volatile("s_waitcnt lgkmcnt(0)" ::: "memory");

  float m_run = -INFINITY, l_run = 0.f;
  float accX0 = 0.f, accX1 = 0.f;   // even kk partial
  float accY0 = 0.f, accY1 = 0.f;   // odd kk partial
  float rope_cur = __builtin_nontemporal_load(rope_pt + s_begin + lane);
  int cur = 0;

#pragma unroll 1
  for (int tile = 0; tile < NTILES; ++tile) {
    const int s0 = s_begin + tile * KB;
    if (tile + 1 < NTILES) issue_tile(cur ^ 1, s0 + KB);
    if (tile == 0 || tile + 1 == NTILES)
      asm volatile("s_waitcnt vmcnt(8)" ::: "memory");
    else
      asm volatile("s_waitcnt vmcnt(16)" ::: "memory");
    __builtin_amdgcn_s_barrier();                 // all waves' rows in LDS

    __builtin_amdgcn_s_setprio(1);
    // prefetch next tile's rope value (hides the ~200cy hit under compute)
    float rope_next = 0.f;
    if (tile + 1 < NTILES) rope_next = __builtin_nontemporal_load(rope_pt + s0 + KB + lane);

    // scores: lane = key within tile, wave = query t; 2 partial sums (ILP)
    const int s = s0 + lane;
    float sc = -INFINITY;
    if (s <= lim) {
      float sumA = rope_cur, sumB = 0.f;
#pragma unroll
      for (int cc = 0; cc < 32; cc += 2) {
        const float4 kv0 = *(const float4*)&kv[cur][lane][((cc + 2 * lane) & 31) << 2];
        const float4 kv1 = *(const float4*)&kv[cur][lane][((cc + 1 + 2 * lane) & 31) << 2];
        sumA += dot4(kv0, *(const float4*)&qc[t][cc << 2]);
        sumB += dot4(kv1, *(const float4*)&qc[t][(cc + 1) << 2]);
      }
      sc = (sumA + sumB) * 0.07216878364870323f;  // 1/sqrt(192)
    }
    const float mt = wmax(sc);
    const float m_new = fmaxf(m_run, mt);
    const float p = expf(sc - m_new);   // masked: expf(-inf)=0
    const float lt = wsum(p);
    const float f = expf(m_run - m_new);
    l_run = l_run * f + lt;
    accX0 *= f; accX1 *= f; accY0 *= f; accY1 *= f;
    m_run = m_new;

    // PV: lane owns dims (2*lane, 2*lane+1); kk in pairs, 2 indep acc chains
    const int c0 = lane >> 1;
    const int off = (lane & 1) << 1;
    const int pu = __float_as_int(p);
#pragma unroll
    for (int kk = 0; kk < KB; kk += 2) {
      const float pv0 = __int_as_float(__builtin_amdgcn_readlane(pu, kk));
      const float pv1 = __int_as_float(__builtin_amdgcn_readlane(pu, kk + 1));
      const float2 vv0 = *(const float2*)&kv[cur][kk][(((c0 + 2 * kk) & 31) << 2) + off];
      const float2 vv1 = *(const float2*)&kv[cur][kk + 1][(((c0 + 2 * (kk + 1)) & 31) << 2) + off];
      accX0 += pv0 * vv0.x;
      accX1 += pv0 * vv0.y;
      accY0 += pv1 * vv1.x;
      accY1 += pv1 * vv1.y;
    }
    __builtin_amdgcn_s_setprio(0);

    // fused copy-out of past rows: LDS -> out_ckv, NON-TEMPORAL stores
#pragma unroll
    for (int u = 0; u < 8; ++u) {
      const int fi = tid + u * 256;
      const int row = fi >> 5;
      const int c   = fi & 31;
      const int ss = s0 + row;
      if (ss < 4092) {
        const vfloat4 v = *(const vfloat4*)&kv[cur][row][((c + 2 * row) & 31) << 2];
        __builtin_nontemporal_store(
            v, (vfloat4*)(out_ckv + ((size_t)(b * 4096 + ss)) * 2048 + h * 128 + (c << 2)));
      }
    }

    __builtin_amdgcn_s_barrier();   // all waves done reading kv[cur]
    cur ^= 1;
    rope_cur = rope_next;
  }

  const size_t base = ((size_t)((b * 16 + h) * 4 + t)) * NSPLIT + sp;
  part_acc[base * 128 + (lane << 1)]     = accX0 + accY0;
  part_acc[base * 128 + (lane << 1) + 1] = accX1 + accY1;
  if (lane == 0) {
    part_ml[base * 2]     = m_run;
    part_ml[base * 2 + 1] = l_run;
  }
}

// ---------------- combine split partials -------------------------------------
__global__ __launch_bounds__(128) void combine_kernel(
    const float* __restrict__ part_acc, const float* __restrict__ part_ml,
    float* __restrict__ merged) {
  const int h = blockIdx.x & 15;
  const int b = blockIdx.x >> 4;
  const int d = threadIdx.x;  // 0..127
#pragma unroll
  for (int t = 0; t < 4; ++t) {
    const size_t base = ((size_t)((b * 16 + h) * 4 + t)) * NSPLIT;
    float mm[NSPLIT], ll[NSPLIT];
    float m = -INFINITY;
#pragma unroll
    for (int sp = 0; sp < NSPLIT; ++sp) {
      mm[sp] = part_ml[(base + sp) * 2];
      ll[sp] = part_ml[(base + sp) * 2 + 1];
      m = fmaxf(m, mm[sp]);
    }
    float den = 0.f, num = 0.f;
#pragma unroll
    for (int sp = 0; sp < NSPLIT; ++sp) {
      const float w = expf(mm[sp] - m);
      den += w * ll[sp];
      num += w * part_acc[(base + sp) * 128 + d];
    }
    merged[((size_t)(b * 4 + t)) * 2048 + h * 128 + d] = num / den;
  }
}

// ---------------- output projection (K=2048) ---------------------------------
__global__ __launch_bounds__(256) void outproj_kernel(
    const float* __restrict__ A, const float* __restrict__ W_o,
    float* __restrict__ out0) {
  const int wave = threadIdx.x >> 6;
  const int lane = threadIdx.x & 63;
  const int jbase = (blockIdx.x * 4 + wave) * 2;  // 2048 cols
  const float* w0 = W_o + (size_t)jbase * 2048;
  const float* w1 = w0 + 2048;

  __shared__ float wlds[4][2][2048];  // 64 KB

#pragma unroll
  for (int m = 0; m < 8; ++m) {
    __builtin_amdgcn_global_load_lds(
        (const __attribute__((address_space(1))) void*)(w0 + (m << 8) + (lane << 2)),
        (__attribute__((address_space(3))) void*)&wlds[wave][0][m << 8], 16, 0, AUX_NT);
    __builtin_amdgcn_global_load_lds(
        (const __attribute__((address_space(1))) void*)(w1 + (m << 8) + (lane << 2)),
        (__attribute__((address_space(3))) void*)&wlds[wave][1][m << 8], 16, 0, AUX_NT);
  }
  __syncthreads();

  float acc0[32], acc1[32];
#pragma unroll
  for (int i = 0; i < 32; ++i) { acc0[i] = 0.f; acc1[i] = 0.f; }

#pragma unroll 1
  for (int m = 0; m < 8; ++m) {
    const int k = (lane << 2) + (m << 8);
    const float4 wa = *(const float4*)&wlds[wave][0][k];
    const float4 wb = *(const float4*)&wlds[wave][1][k];
#pragma unroll
    for (int i = 0; i < 32; ++i) {
      const float4 a = *(const float4*)(A + i * 2048 + k);
      acc0[i] += dot4(a, wa);
      acc1[i] += dot4(a, wb);
    }
  }
#pragma unroll
  for (int i = 0; i < 32; ++i) { acc0[i] = wsum(acc0[i]); acc1[i] = wsum(acc1[i]); }
  float myval = 0.f;
#pragma unroll
  for (int i = 0; i < 32; ++i) {
    myval = (lane == i)      ? acc0[i] : myval;
    myval = (lane == i + 32) ? acc1[i] : myval;
  }
  const int mi = lane & 31;
  const int col = jbase + (lane >> 5);
  out0[(size_t)mi * 2048 + col] = myval;
}

extern "C" void kernel_launch(void* const* d_in, const int* in_sizes, int n_in,
                              void* d_out, int out_size, void* d_ws, size_t ws_size,
                              hipStream_t stream) {
  const float* hidden   = (const float*)d_in[0];
  const float* ckv_past = (const float*)d_in[1];
  const float* kr_past  = (const float*)d_in[2];
  // d_in[3] attention_mask: replicated analytically (causal, offset PAST)
  const float* W_dq  = (const float*)d_in[4];
  const float* W_uq  = (const float*)d_in[5];
  const float* W_qr  = (const float*)d_in[6];
  const float* W_dkv = (const float*)d_in[7];
  const float* W_kr  = (const float*)d_in[8];
  const float* W_o   = (const float*)d_in[9];

  float* out0    = (float*)d_out;                       // (8,4,2048)
  float* out_ckv = out0 + (size_t)32 * 2048;            // (8,4096,2048)
  float* out_kr  = out_ckv + (size_t)8 * 4096 * 2048;   // (8,4096,64)

  float* ws       = (float*)d_ws;
  float* ws_cq    = ws;                                  // 32*512
  float* ws_qc    = ws_cq + 32 * 512;                    // 32*2048
  float* ws_qr    = ws_qc + 32 * 2048;                   // 32*1024
  float* part_acc = ws_qr + 32 * 1024;                   // 8*16*4*NSPLIT*128
  float* part_ml  = part_acc + (size_t)8 * 16 * 4 * NSPLIT * 128;
  float* merged   = part_ml + (size_t)8 * 16 * 4 * NSPLIT * 2;   // 32*2048
  float* rope     = merged + 32 * 2048;                  // 8*64*4096 floats

  hipLaunchKernelGGL(proj1_kernel, dim3(328), dim3(256), 0, stream,
                     hidden, W_dq, W_dkv, W_kr, ws_cq, out_ckv, out_kr);
  hipLaunchKernelGGL(proj2_kernel, dim3(384), dim3(256), 0, stream,
                     ws_cq, W_uq, W_qr, ws_qc, ws_qr);
  hipLaunchKernelGGL(rope_kernel, dim3(64, 8), dim3(256), 0, stream,
                     kr_past, out_kr, ws_qr, rope);
  hipLaunchKernelGGL(attn_kernel, dim3(NSPLIT, 16, 8), dim3(256), 0, stream,
                     ckv_past, out_ckv, ws_qc, rope, part_acc, part_ml);
  hipLaunchKernelGGL(combine_kernel, dim3(128), dim3(128), 0, stream,
                     part_acc, part_ml, merged);
  hipLaunchKernelGGL(outproj_kernel, dim3(256), dim3(256), 0, stream,
                     merged, W_o, out0);
}